// Round 1
// baseline (102.427 us; speedup 1.0000x reference)
//
#include <hip/hip_runtime.h>
#include <math.h>

// Problem constants (from reference)
#define B_  4
#define P_  512
#define K_  4
#define H_  200
#define W_  336
#define A_  14
#define PS_ 56
#define SCALE_ 0.25f

__global__ __launch_bounds__(256) void blender_kernel(
    const float* __restrict__ bases,   // [B,K,H,W]
    const float* __restrict__ boxes,   // [B,P,4]
    const float* __restrict__ attn,    // [B,P,K,A,A]
    float* __restrict__ out)           // [B,P,PS,PS]
{
    const int bp = blockIdx.x;          // b*P_ + p
    const int b  = bp / P_;

    __shared__ float tile[K_][A_ * A_]; // 784 floats = 3.1 KB

    // Stage this (b,p)'s attention tile into LDS (coalesced)
    const float* ap = attn + (size_t)bp * (K_ * A_ * A_);
    for (int i = threadIdx.x; i < K_ * A_ * A_; i += blockDim.x) {
        tile[i / (A_ * A_)][i % (A_ * A_)] = ap[i];
    }

    // Box parameters (cheap, every thread computes)
    const float* bx = boxes + (size_t)bp * 4;
    const float x1 = bx[0] * SCALE_;
    const float y1 = bx[1] * SCALE_;
    const float x2 = bx[2] * SCALE_;
    const float y2 = bx[3] * SCALE_;
    const float bw = fmaxf(x2 - x1, 1.0f) * (1.0f / PS_);
    const float bh = fmaxf(y2 - y1, 1.0f) * (1.0f / PS_);

    __syncthreads();

    const float* base_b = bases + (size_t)b * (K_ * H_ * W_);
    float* outp = out + (size_t)bp * (PS_ * PS_);

    const float r = (float)(A_ - 1) / (float)(PS_ - 1);  // 13/55

    for (int idx = threadIdx.x; idx < PS_ * PS_; idx += blockDim.x) {
        const int py = idx / PS_;
        const int px = idx % PS_;

        // ---- RoIAlign sample (k-independent coords, sampling_ratio=1) ----
        const float sx = x1 + (px + 0.5f) * bw;
        const float sy = y1 + (py + 0.5f) * bh;
        const bool valid = (sy > -1.0f) && (sy < (float)H_) &&
                           (sx > -1.0f) && (sx < (float)W_);
        const float cy = fminf(fmaxf(sy, 0.0f), (float)(H_ - 1));
        const float cx = fminf(fmaxf(sx, 0.0f), (float)(W_ - 1));
        const int y0 = (int)cy;               // cy >= 0 -> trunc == floor
        const int x0 = (int)cx;
        const int y1i = min(y0 + 1, H_ - 1);
        const int x1i = min(x0 + 1, W_ - 1);
        const float ly = cy - (float)y0;
        const float lx = cx - (float)x0;
        const float w00 = (1.0f - ly) * (1.0f - lx);
        const float w01 = (1.0f - ly) * lx;
        const float w10 = ly * (1.0f - lx);
        const float w11 = ly * lx;
        const float vscale = valid ? 1.0f : 0.0f;

        // ---- attn 14->56 resize coords (align_corners=True) ----
        const float srcx = (float)px * r;
        const float srcy = (float)py * r;
        int ix0 = (int)srcx; ix0 = min(ix0, A_ - 2);
        int iy0 = (int)srcy; iy0 = min(iy0, A_ - 2);
        const float tx = srcx - (float)ix0;
        const float ty = srcy - (float)iy0;
        const float a00 = (1.0f - ty) * (1.0f - tx);
        const float a01 = (1.0f - ty) * tx;
        const float a10 = ty * (1.0f - tx);
        const float a11 = ty * tx;

        float av[K_], rv[K_];
        float m = -1e30f;
        #pragma unroll
        for (int k = 0; k < K_; ++k) {
            const float* t = tile[k];
            const float a = t[iy0 * A_ + ix0]     * a00
                          + t[iy0 * A_ + ix0 + 1] * a01
                          + t[(iy0 + 1) * A_ + ix0]     * a10
                          + t[(iy0 + 1) * A_ + ix0 + 1] * a11;
            av[k] = a;
            m = fmaxf(m, a);

            const float* f = base_b + (size_t)k * (H_ * W_);
            const float v = f[y0 * W_ + x0]  * w00
                          + f[y0 * W_ + x1i] * w01
                          + f[y1i * W_ + x0]  * w10
                          + f[y1i * W_ + x1i] * w11;
            rv[k] = v * vscale;
        }

        // softmax over K, then weighted sum
        float e[K_];
        float s = 0.0f;
        #pragma unroll
        for (int k = 0; k < K_; ++k) { e[k] = __expf(av[k] - m); s += e[k]; }
        const float inv = 1.0f / s;
        float acc = 0.0f;
        #pragma unroll
        for (int k = 0; k < K_; ++k) acc += e[k] * inv * rv[k];

        outp[idx] = acc;
    }
}

extern "C" void kernel_launch(void* const* d_in, const int* in_sizes, int n_in,
                              void* d_out, int out_size, void* d_ws, size_t ws_size,
                              hipStream_t stream) {
    const float* bases = (const float*)d_in[0];  // [B,K,H,W]
    const float* boxes = (const float*)d_in[1];  // [B,P,4]
    const float* attn  = (const float*)d_in[2];  // [B,P,K,A,A]
    float* out = (float*)d_out;                  // [B,P,PS,PS]

    dim3 grid(B_ * P_);
    dim3 block(256);
    blender_kernel<<<grid, block, 0, stream>>>(bases, boxes, attn, out);
}